// Round 10
// baseline (618.684 us; speedup 1.0000x reference)
//
#include <hip/hip_runtime.h>

// GraphSAGE on MI355X — fp32 I/O, split-bf16 MFMA GEMMs, fused aggregate+GEMM.
// Stages: detect edge dtype -> CSR build (count / 3-kernel scan / fill+nt-store)
//         -> 3x fused(aggregate->LDS->dual GEMM) with decoder fused into layer 3.

#define N_NODES 50000
#define N_EDGES 800000
#define D 128
#define NB ((N_NODES + 255) / 256)   // 196 scan blocks
#define NTILES (N_NODES / 16)        // 3125 row tiles

typedef __bf16 bf16x8 __attribute__((ext_vector_type(8)));
typedef float f32x4 __attribute__((ext_vector_type(4)));

struct bf16pair { bf16x8 hi, lo; };

__device__ inline bf16pair split8v(f32x4 a, f32x4 b) {
    bf16pair r;
#pragma unroll
    for (int i = 0; i < 4; ++i) {
        float v = a[i];
        __bf16 h = (__bf16)v;
        r.hi[i] = h;
        r.lo[i] = (__bf16)(v - (float)h);
    }
#pragma unroll
    for (int i = 0; i < 4; ++i) {
        float v = b[i];
        __bf16 h = (__bf16)v;
        r.hi[4 + i] = h;
        r.lo[4 + i] = (__bf16)(v - (float)h);
    }
    return r;
}

__device__ inline bf16pair split8(const float* __restrict__ p) {
    return split8v(*reinterpret_cast<const f32x4*>(p),
                   *reinterpret_cast<const f32x4*>(p + 4));
}

// ---------- edge dtype detect: int64 edge values < 2^31 have zero high words ----------
__global__ void detect_kernel(const int* __restrict__ ew, int* __restrict__ flag) {
    __shared__ int s;
    if (threadIdx.x == 0) s = 0;
    __syncthreads();
    int v = 0;
    for (int i = threadIdx.x; i < 1024; i += 256) v |= ew[2 * i + 1];
    if (v) atomicOr(&s, 1);
    __syncthreads();
    if (threadIdx.x == 0) flag[0] = s ? 1 : 2;   // words per element
}

// ---------- CSR build ----------
__global__ void count_kernel(const int* __restrict__ ew, const int* __restrict__ flag,
                             int* __restrict__ cnt) {
    int st = flag[0];
    int e = blockIdx.x * blockDim.x + threadIdx.x;
    if (e < N_EDGES) {
        int d = ew[(size_t)st * (N_EDGES + e)];
        atomicAdd(&cnt[d], 1);
    }
}

// scan1: per-block (256 entries) exclusive prefix into off, block sums into bsum
__global__ __launch_bounds__(256) void scan1_kernel(const int* __restrict__ cnt,
                                                    int* __restrict__ off,
                                                    int* __restrict__ bsum) {
    const int tid = threadIdx.x, lane = tid & 63, wid = tid >> 6;
    const int i = blockIdx.x * 256 + tid;
    int orig = (i < N_NODES) ? cnt[i] : 0;
    int v = orig;
#pragma unroll
    for (int d = 1; d < 64; d <<= 1) {
        int t = __shfl_up(v, d, 64);
        if (lane >= d) v += t;
    }
    __shared__ int ws[4];
    if (lane == 63) ws[wid] = v;
    __syncthreads();
    int base = 0;
    for (int w = 0; w < wid; ++w) base += ws[w];
    v += base;                            // inclusive in-block prefix
    if (i < N_NODES) off[i] = v - orig;   // exclusive (block-local)
    if (tid == 255) bsum[blockIdx.x] = v; // block total
}

// scan2: single block scans NB block sums -> exclusive bases; writes off[N]=total
__global__ __launch_bounds__(256) void scan2_kernel(const int* __restrict__ bsum,
                                                    int* __restrict__ bbase,
                                                    int* __restrict__ off) {
    const int tid = threadIdx.x, lane = tid & 63, wid = tid >> 6;
    int orig = (tid < NB) ? bsum[tid] : 0;
    int v = orig;
#pragma unroll
    for (int d = 1; d < 64; d <<= 1) {
        int t = __shfl_up(v, d, 64);
        if (lane >= d) v += t;
    }
    __shared__ int ws[4];
    if (lane == 63) ws[wid] = v;
    __syncthreads();
    int base = 0;
    for (int w = 0; w < wid; ++w) base += ws[w];
    v += base;
    if (tid < NB) bbase[tid] = v - orig;   // exclusive block base
    if (tid == NB - 1) off[N_NODES] = v;   // total == N_EDGES
}

// scan3: add block base, fill cursor
__global__ __launch_bounds__(256) void scan3_kernel(int* __restrict__ off,
                                                    const int* __restrict__ bbase,
                                                    int* __restrict__ cursor) {
    int i = blockIdx.x * 256 + threadIdx.x;
    if (i < N_NODES) {
        int v = off[i] + bbase[blockIdx.x];
        off[i] = v;
        cursor[i] = v;
    }
}

__global__ void fill_kernel(const int* __restrict__ ew, const int* __restrict__ flag,
                            int* __restrict__ cursor, int* __restrict__ csr) {
    int st = flag[0];
    int e = blockIdx.x * blockDim.x + threadIdx.x;
    if (e < N_EDGES) {
        int d = ew[(size_t)st * (N_EDGES + e)];
        int sidx = ew[(size_t)st * e];
        int pos = atomicAdd(&cursor[d], 1);
        __builtin_nontemporal_store(sidx, &csr[pos]);
    }
}

// ---------- fused: segment-mean aggregate (16-node tile -> LDS) + dual GEMM ----------
// out = mean_aggr(hin) @ W1^T + hin @ W2^T + b (optional relu).
// If dec != nullptr: also dec[i][0..1] = out_row_i @ Wo^T + bo (decoder fused, layer 3).
// MFMA 16x16x32 bf16 fragment maps: A row=lane&15, k=8*(lane>>4)+i; B col=lane&15 same k;
// D col=lane&15, row=4*(lane>>4)+r (m89-verified). fp32 accuracy via split hi/lo bf16.
// LDS agg tile uses 8-float-unit rotation (unit+row)&15 to break the D=128 bank conflict.
__global__ __launch_bounds__(256) void fused_kernel(const float* __restrict__ hin,
                                                    const int* __restrict__ off,
                                                    const int* __restrict__ csr,
                                                    const float* __restrict__ W1,
                                                    const float* __restrict__ W2,
                                                    const float* __restrict__ bias,
                                                    float* __restrict__ hout,
                                                    int do_relu,
                                                    const float* __restrict__ Wo,
                                                    const float* __restrict__ bo,
                                                    float* __restrict__ dec) {
    __shared__ float sAgg[16 * 128];
    __shared__ float part[4][16][2];
    const int lane = threadIdx.x & 63;
    const int wid = threadIdx.x >> 6;     // 4 waves: col ranges of 32
    const int colbase = wid * 32;
    const int lr = lane & 15;
    const int lg = lane >> 4;

    // W fragments resident in registers for the whole kernel
    bf16pair B1[2][4], B2[2][4];
    for (int ct = 0; ct < 2; ++ct) {
        int j = colbase + ct * 16 + lr;
        for (int kk = 0; kk < 4; ++kk) {
            int k = kk * 32 + lg * 8;
            B1[ct][kk] = split8(W1 + j * D + k);
            B2[ct][kk] = split8(W2 + j * D + k);
        }
    }
    float bb0 = bias[colbase + lr];
    float bb1 = bias[colbase + 16 + lr];
    const int decode = (dec != nullptr);
    float wo00 = 0.f, wo01 = 0.f, wo10 = 0.f, wo11 = 0.f, bo0 = 0.f, bo1 = 0.f;
    if (decode) {
        wo00 = Wo[colbase + lr];       wo01 = Wo[colbase + 16 + lr];
        wo10 = Wo[D + colbase + lr];   wo11 = Wo[D + colbase + 16 + lr];
        bo0 = bo[0];                   bo1 = bo[1];
    }

    for (int rt = blockIdx.x; rt < NTILES; rt += gridDim.x) {
        __syncthreads();   // S1: sAgg/part free from previous iteration's readers
        // ---- phase 1: each wave aggregates 4 of the tile's 16 rows ----
        for (int rr = 0; rr < 4; ++rr) {
            int row = wid * 4 + rr;
            int node = rt * 16 + row;
            int beg = off[node], end = off[node + 1];
            float ax = 0.f, ay = 0.f;
            int j = beg;
            for (; j + 7 < end; j += 8) {
                int s0 = csr[j],     s1 = csr[j + 1], s2 = csr[j + 2], s3 = csr[j + 3];
                int s4 = csr[j + 4], s5 = csr[j + 5], s6 = csr[j + 6], s7 = csr[j + 7];
                float2 v0 = *reinterpret_cast<const float2*>(hin + (size_t)s0 * D + lane * 2);
                float2 v1 = *reinterpret_cast<const float2*>(hin + (size_t)s1 * D + lane * 2);
                float2 v2 = *reinterpret_cast<const float2*>(hin + (size_t)s2 * D + lane * 2);
                float2 v3 = *reinterpret_cast<const float2*>(hin + (size_t)s3 * D + lane * 2);
                float2 v4 = *reinterpret_cast<const float2*>(hin + (size_t)s4 * D + lane * 2);
                float2 v5 = *reinterpret_cast<const float2*>(hin + (size_t)s5 * D + lane * 2);
                float2 v6 = *reinterpret_cast<const float2*>(hin + (size_t)s6 * D + lane * 2);
                float2 v7 = *reinterpret_cast<const float2*>(hin + (size_t)s7 * D + lane * 2);
                ax += (v0.x + v1.x) + (v2.x + v3.x) + (v4.x + v5.x) + (v6.x + v7.x);
                ay += (v0.y + v1.y) + (v2.y + v3.y) + (v4.y + v5.y) + (v6.y + v7.y);
            }
            for (; j < end; ++j) {
                int s = csr[j];
                float2 v = *reinterpret_cast<const float2*>(hin + (size_t)s * D + lane * 2);
                ax += v.x;
                ay += v.y;
            }
            int c = end - beg;
            if (c < 1) c = 1;
            float fc = (float)c;
            // swizzled LDS store: col = lane*2 lives in 8-float unit (lane>>2), rotated by row
            int unit = ((lane >> 2) + row) & 15;
            int phys = row * 128 + unit * 8 + (lane & 3) * 2;
            sAgg[phys] = ax / fc;
            sAgg[phys + 1] = ay / fc;
        }
        __syncthreads();   // S2: agg tile ready
        // ---- phase 2: dual GEMM on this 16-row tile ----
        bf16pair Af1[4], Af2[4];
        for (int kk = 0; kk < 4; ++kk) {
            int k = kk * 32 + lg * 8;
            int unit = ((k >> 3) + lr) & 15;
            const float* ap = &sAgg[lr * 128 + unit * 8];
            Af1[kk] = split8v(*reinterpret_cast<const f32x4*>(ap),
                              *reinterpret_cast<const f32x4*>(ap + 4));
            Af2[kk] = split8(hin + (size_t)(rt * 16 + lr) * D + k);
        }
        float p0[4] = {0.f, 0.f, 0.f, 0.f}, p1[4] = {0.f, 0.f, 0.f, 0.f};
        for (int ct = 0; ct < 2; ++ct) {
            float bb = ct ? bb1 : bb0;
            f32x4 acc = {bb, bb, bb, bb};
            for (int kk = 0; kk < 4; ++kk) {
                acc = __builtin_amdgcn_mfma_f32_16x16x32_bf16(Af1[kk].hi, B1[ct][kk].hi, acc, 0, 0, 0);
                acc = __builtin_amdgcn_mfma_f32_16x16x32_bf16(Af1[kk].lo, B1[ct][kk].hi, acc, 0, 0, 0);
                acc = __builtin_amdgcn_mfma_f32_16x16x32_bf16(Af1[kk].hi, B1[ct][kk].lo, acc, 0, 0, 0);
                acc = __builtin_amdgcn_mfma_f32_16x16x32_bf16(Af2[kk].hi, B2[ct][kk].hi, acc, 0, 0, 0);
                acc = __builtin_amdgcn_mfma_f32_16x16x32_bf16(Af2[kk].lo, B2[ct][kk].hi, acc, 0, 0, 0);
                acc = __builtin_amdgcn_mfma_f32_16x16x32_bf16(Af2[kk].hi, B2[ct][kk].lo, acc, 0, 0, 0);
            }
            float woa = ct ? wo01 : wo00;
            float wob = ct ? wo11 : wo10;
            int col = colbase + ct * 16 + lr;
            for (int r = 0; r < 4; ++r) {
                float v = acc[r];
                if (do_relu) v = fmaxf(v, 0.0f);
                int orow = rt * 16 + lg * 4 + r;
                hout[(size_t)orow * D + col] = v;
                p0[r] += v * woa;
                p1[r] += v * wob;
            }
        }
        if (decode) {
            // reduce partial decoder dots across the 16 lanes (lr) of each row group
#pragma unroll
            for (int m = 1; m < 16; m <<= 1) {
#pragma unroll
                for (int r = 0; r < 4; ++r) {
                    p0[r] += __shfl_xor(p0[r], m, 64);
                    p1[r] += __shfl_xor(p1[r], m, 64);
                }
            }
            if (lr == 0) {
#pragma unroll
                for (int r = 0; r < 4; ++r) {
                    part[wid][lg * 4 + r][0] = p0[r];
                    part[wid][lg * 4 + r][1] = p1[r];
                }
            }
            __syncthreads();   // S3: partials ready
            if (wid == 0 && lane < 16) {
                float s0 = part[0][lane][0] + part[1][lane][0] + part[2][lane][0] + part[3][lane][0] + bo0;
                float s1 = part[0][lane][1] + part[1][lane][1] + part[2][lane][1] + part[3][lane][1] + bo1;
                float2 o;
                o.x = s0;
                o.y = s1;
                *reinterpret_cast<float2*>(dec + (size_t)(rt * 16 + lane) * 2) = o;
            }
        }
    }
}

extern "C" void kernel_launch(void* const* d_in, const int* in_sizes, int n_in,
                              void* d_out, int out_size, void* d_ws, size_t ws_size,
                              hipStream_t stream) {
    const float* x   = (const float*)d_in[0];
    const int* ew    = (const int*)d_in[1];
    const float* Wl1 = (const float*)d_in[2];
    const float* Wr1 = (const float*)d_in[3];
    const float* b1  = (const float*)d_in[4];
    const float* Wl2 = (const float*)d_in[5];
    const float* Wr2 = (const float*)d_in[6];
    const float* b2  = (const float*)d_in[7];
    const float* Wl3 = (const float*)d_in[8];
    const float* Wr3 = (const float*)d_in[9];
    const float* b3  = (const float*)d_in[10];
    const float* Wo  = (const float*)d_in[11];
    const float* bo  = (const float*)d_in[12];

    char* ws = (char*)d_ws;
    size_t o = 0;
    auto alloc = [&](size_t bytes) {
        char* p = ws + o;
        o += (bytes + 255) & ~(size_t)255;
        return p;
    };
    int* flag   = (int*)alloc(4);
    int* cnt    = (int*)alloc((size_t)N_NODES * 4);
    int* off    = (int*)alloc((size_t)(N_NODES + 1) * 4);
    int* cursor = (int*)alloc((size_t)N_NODES * 4);
    int* csr    = (int*)alloc((size_t)N_EDGES * 4);
    int* bsum   = (int*)alloc((size_t)NB * 4);
    int* bbase  = (int*)alloc((size_t)NB * 4);
    float* h1   = (float*)alloc((size_t)N_NODES * D * 4);
    float* h2   = (float*)alloc((size_t)N_NODES * D * 4);

    float* outp = (float*)d_out;                 // [N,2]
    float* h3   = outp + (size_t)N_NODES * 2;    // [N,128], tail of d_out

    hipMemsetAsync(cnt, 0, (size_t)N_NODES * 4, stream);
    detect_kernel<<<1, 256, 0, stream>>>(ew, flag);
    count_kernel<<<(N_EDGES + 255) / 256, 256, 0, stream>>>(ew, flag, cnt);
    scan1_kernel<<<NB, 256, 0, stream>>>(cnt, off, bsum);
    scan2_kernel<<<1, 256, 0, stream>>>(bsum, bbase, off);
    scan3_kernel<<<NB, 256, 0, stream>>>(off, bbase, cursor);
    fill_kernel<<<(N_EDGES + 255) / 256, 256, 0, stream>>>(ew, flag, cursor, csr);

    fused_kernel<<<512, 256, 0, stream>>>(x, off, csr, Wl1, Wr1, b1, h1, 1,
                                          nullptr, nullptr, nullptr);
    fused_kernel<<<512, 256, 0, stream>>>(h1, off, csr, Wl2, Wr2, b2, h2, 1,
                                          nullptr, nullptr, nullptr);
    fused_kernel<<<512, 256, 0, stream>>>(h2, off, csr, Wl3, Wr3, b3, h3, 0,
                                          Wo, bo, outp);
}